// Round 14
// baseline (2643.211 us; speedup 1.0000x reference)
//
#include <hip/hip_runtime.h>

#define NN 100000
#define NE 1600000
#define NG 128
#define DIN 20
#define DEMB 300
#define DHID 600
#define DOUT 64
// padded dims
#define DIN_P 32
#define EMB_P 320   // activation storage width (multiple of 64)
#define HID_P 640
#define EMB_G 384   // gemm2 N-dim padding (multiple of 128)
#define SCAN_BLK 392  // ceil(NN/256)

static const float BN_EPS_F = 1e-5f;

typedef _Float16 f16x8 __attribute__((ext_vector_type(8)));
typedef float f32x4 __attribute__((ext_vector_type(4)));

// async global->LDS, 16B per lane; LDS dst = wave-uniform base + lane*16
__device__ __forceinline__ void gload_lds16(const void* g, const void* l) {
  __builtin_amdgcn_global_load_lds(
      (const __attribute__((address_space(1))) unsigned int*)(unsigned long long)g,
      (__attribute__((address_space(3))) unsigned int*)(unsigned long long)(unsigned int)(unsigned long long)l,
      16, 0, 0);
}

// ---------------- CSR build (once per call) ----------------

__global__ void count_edges_kernel(const int* __restrict__ dst, const float* __restrict__ ef,
                                   int* __restrict__ counts, float* __restrict__ esum) {
  int e = blockIdx.x * blockDim.x + threadIdx.x;
  if (e >= NE) return;
  int v = dst[e];
  atomicAdd(&counts[v], 1);
  atomicAdd(&esum[v], ef[e]);
}

// 3-phase exclusive scan of counts -> row_ptr/cursor
__global__ __launch_bounds__(256) void scan_part1(const int* __restrict__ counts,
                                                  int* __restrict__ bsums) {
  __shared__ int red[256];
  int t = threadIdx.x;
  int i = blockIdx.x * 256 + t;
  red[t] = (i < NN) ? counts[i] : 0;
  __syncthreads();
  for (int s = 128; s > 0; s >>= 1) {
    if (t < s) red[t] += red[t + s];
    __syncthreads();
  }
  if (t == 0) bsums[blockIdx.x] = red[0];
}

__global__ __launch_bounds__(512) void scan_part2(const int* __restrict__ bsums,
                                                  int* __restrict__ boffs) {
  __shared__ int sc[512];
  int t = threadIdx.x;
  int v = (t < SCAN_BLK) ? bsums[t] : 0;
  sc[t] = v;
  __syncthreads();
  for (int off = 1; off < 512; off <<= 1) {
    int u = (t >= off) ? sc[t - off] : 0;
    __syncthreads();
    sc[t] += u;
    __syncthreads();
  }
  if (t < SCAN_BLK) boffs[t] = sc[t] - v;  // exclusive
}

__global__ __launch_bounds__(256) void scan_part3(const int* __restrict__ counts,
                                                  const int* __restrict__ boffs,
                                                  int* __restrict__ row_ptr,
                                                  int* __restrict__ cursor) {
  __shared__ int sc[256];
  int t = threadIdx.x;
  int i = blockIdx.x * 256 + t;
  int v = (i < NN) ? counts[i] : 0;
  sc[t] = v;
  __syncthreads();
  for (int off = 1; off < 256; off <<= 1) {
    int u = (t >= off) ? sc[t - off] : 0;
    __syncthreads();
    sc[t] += u;
    __syncthreads();
  }
  if (i < NN) {
    int excl = sc[t] - v + boffs[blockIdx.x];
    row_ptr[i] = excl;
    cursor[i] = excl;
  }
  if (i == NN - 1) row_ptr[NN] = NE;
}

__global__ void scatter_kernel(const int* __restrict__ src, const int* __restrict__ dst,
                               int* __restrict__ cursor, int* __restrict__ csr_src) {
  int e = blockIdx.x * blockDim.x + threadIdx.x;
  if (e >= NE) return;
  int pos = atomicAdd(&cursor[dst[e]], 1);
  csr_src[pos] = src[e];
}

// ---------------- ONE fused repack kernel: all weights + biases ----------------
// ranges: [0,T0) w1t0 | [T0,T1) w1t x4 | [T1,T2) w2t x5 | [T2,T3) b1p x5 | [T3,T4) b2p x5

#define RT0 (HID_P * DIN_P)                 // 20480
#define RT1 (RT0 + 4 * HID_P * EMB_P)       // 839680
#define RT2 (RT1 + 5 * EMB_G * HID_P)       // 2068480
#define RT3 (RT2 + 5 * HID_P)               // 2071680
#define RT4 (RT3 + 5 * EMB_G)               // 2073600

__global__ void repack_all_kernel(const float* __restrict__ w1_0, const float* __restrict__ w1s,
                                  const float* __restrict__ w2_0, const float* __restrict__ w2s,
                                  const float* __restrict__ b1_0, const float* __restrict__ b1s,
                                  const float* __restrict__ b2_0, const float* __restrict__ b2s,
                                  _Float16* __restrict__ w1t0, _Float16* __restrict__ w1t,
                                  _Float16* __restrict__ w2t, float* __restrict__ b1p,
                                  float* __restrict__ b2p) {
  int idx = blockIdx.x * blockDim.x + threadIdx.x;
  if (idx >= RT4) return;
  if (idx < RT0) {
    int n = idx / DIN_P, k = idx - n * DIN_P;
    float v = (n < DHID && k < DIN) ? w1_0[(size_t)k * DHID + n] : 0.f;
    w1t0[idx] = (_Float16)v;
  } else if (idx < RT1) {
    int r = idx - RT0;
    int l = r / (HID_P * EMB_P);
    int q = r - l * (HID_P * EMB_P);
    int n = q / EMB_P, k = q - n * EMB_P;
    const float* w = w1s + (size_t)l * DEMB * DHID;
    float v = (n < DHID && k < DEMB) ? w[(size_t)k * DHID + n] : 0.f;
    w1t[r] = (_Float16)v;
  } else if (idx < RT2) {
    int r = idx - RT1;
    int l = r / (EMB_G * HID_P);
    int q = r - l * (EMB_G * HID_P);
    int n = q / HID_P, k = q - n * HID_P;
    const float* w = (l == 0) ? w2_0 : w2s + (size_t)(l - 1) * DHID * DEMB;
    float v = (n < DEMB && k < DHID) ? w[(size_t)k * DEMB + n] : 0.f;
    w2t[r] = (_Float16)v;
  } else if (idx < RT3) {
    int r = idx - RT2;
    int l = r / HID_P, i = r - l * HID_P;
    const float* b = (l == 0) ? b1_0 : b1s + (size_t)(l - 1) * DHID;
    b1p[r] = (i < DHID) ? b[i] : 0.f;
  } else {
    int r = idx - RT3;
    int l = r / EMB_G, i = r - l * EMB_G;
    const float* b = (l == 0) ? b2_0 : b2s + (size_t)(l - 1) * DEMB;
    b2p[r] = (i < DEMB) ? b[i] : 0.f;
  }
}

// ---------------- layer-0 spmm: fp32 x[N][20] -> fp16 agg0[N][32], half-wave per node ----

__global__ __launch_bounds__(256) void spmm0_kernel(const float* __restrict__ x,
                                                    const int* __restrict__ row_ptr,
                                                    const int* __restrict__ csr_src,
                                                    const float* __restrict__ esum,
                                                    _Float16* __restrict__ out) {
  int node = (blockIdx.x * blockDim.x + threadIdx.x) >> 5;
  int lane = threadIdx.x & 31;
  if (node >= NN) return;
  int beg = row_ptr[node], end = row_ptr[node + 1];
  float acc = 0.f;
  int j = beg;
  for (; j + 1 < end; j += 2) {
    int s0 = csr_src[j], s1 = csr_src[j + 1];
    if (lane < DIN) {
      acc += x[(size_t)s0 * DIN + lane];
      acc += x[(size_t)s1 * DIN + lane];
    }
  }
  if (j < end) {
    int s0 = csr_src[j];
    if (lane < DIN) acc += x[(size_t)s0 * DIN + lane];
  }
  float v = (lane < DIN) ? acc + esum[node] : 0.f;
  out[(size_t)node * DIN_P + lane] = (_Float16)v;
}

// ---------------- fused spmm (layers 1..4): gather raw h2 fp16, BN-finalize+apply inline ----
// out[v,c] = sc[c]*sum_u h2[u,c] + deg(v)*sh[c] + esum[v],  sc/sh from raw stats (prev layer)

__global__ __launch_bounds__(256) void spmm_f16_kernel(const _Float16* __restrict__ x,
                                                       const float* __restrict__ stats,
                                                       const float* __restrict__ gamma,
                                                       const float* __restrict__ beta,
                                                       const int* __restrict__ row_ptr,
                                                       const int* __restrict__ csr_src,
                                                       const float* __restrict__ esum,
                                                       _Float16* __restrict__ out) {
  int wid = (blockIdx.x * blockDim.x + threadIdx.x) >> 6;
  int lane = threadIdx.x & 63;
  if (wid >= NN) return;
  int beg = row_ptr[wid], end = row_ptr[wid + 1];
  float deg = (float)(end - beg);
  float es = esum[wid];
  if (lane >= 40) return;
  // inline BN finalize for this lane's 8 columns
  float sc[8], sh[8];
#pragma unroll
  for (int i = 0; i < 8; ++i) {
    int c = lane * 8 + i;
    if (c < DEMB) {
      float mu = stats[c] * (1.f / (float)NN);
      float var = fmaxf(stats[EMB_G + c] * (1.f / (float)NN) - mu * mu, 0.f);
      float s = gamma[c] * rsqrtf(var + BN_EPS_F);
      sc[i] = s;
      sh[i] = beta[c] - mu * s;
    } else {
      sc[i] = 0.f;
      sh[i] = 0.f;
    }
  }
  const f16x8* xb = (const f16x8*)x;
  float acc[8] = {};
  int j = beg;
  for (; j + 7 < end; j += 8) {
    int s0 = csr_src[j + 0], s1 = csr_src[j + 1], s2 = csr_src[j + 2], s3 = csr_src[j + 3];
    int s4 = csr_src[j + 4], s5 = csr_src[j + 5], s6 = csr_src[j + 6], s7 = csr_src[j + 7];
    f16x8 v0 = xb[(size_t)s0 * 40 + lane];
    f16x8 v1 = xb[(size_t)s1 * 40 + lane];
    f16x8 v2 = xb[(size_t)s2 * 40 + lane];
    f16x8 v3 = xb[(size_t)s3 * 40 + lane];
    f16x8 v4 = xb[(size_t)s4 * 40 + lane];
    f16x8 v5 = xb[(size_t)s5 * 40 + lane];
    f16x8 v6 = xb[(size_t)s6 * 40 + lane];
    f16x8 v7 = xb[(size_t)s7 * 40 + lane];
#pragma unroll
    for (int i = 0; i < 8; ++i) {
      acc[i] += ((float)v0[i] + (float)v1[i]) + ((float)v2[i] + (float)v3[i]) +
                ((float)v4[i] + (float)v5[i]) + ((float)v6[i] + (float)v7[i]);
    }
  }
  for (; j < end; ++j) {
    f16x8 v0 = xb[(size_t)csr_src[j] * 40 + lane];
#pragma unroll
    for (int i = 0; i < 8; ++i) acc[i] += (float)v0[i];
  }
  f16x8 o;
#pragma unroll
  for (int i = 0; i < 8; ++i)
    o[i] = (_Float16)(acc[i] * sc[i] + deg * sh[i] + es);
  ((f16x8*)(out))[(size_t)wid * 40 + lane] = o;
}

// ---------------- pipelined 128x128 MFMA GEMM + XCD swizzle + LDS-staged epilogue (R13) ----

template <bool RELU, bool STATS, int GX>
__global__ __launch_bounds__(256, 4) void gemm_pipe_kernel(const _Float16* __restrict__ A,
                                                           const _Float16* __restrict__ Bt,
                                                           const float* __restrict__ bias,
                                                           _Float16* __restrict__ C,
                                                           int M, int K, int ldC, int NREAL,
                                                           int MT,
                                                           float* __restrict__ stats) {
  __shared__ __align__(16) _Float16 lds[2][16 * 512];  // 2 x 16 KB; reused as 4 x 8 KB epilogue staging
  const int id = blockIdx.x;
  const int grp = id / (GX * 8);
  const int rem = id - grp * (GX * 8);
  const int bx = rem >> 3;
  const int by = grp * 8 + (rem & 7);
  if (by >= MT) return;

  const int t = threadIdx.x;
  const int wv = t >> 6;
  const int lane = t & 63;
  const int fm = lane & 15;
  const int k8 = (lane >> 4) * 8;
  const int m0 = by * 128;
  const int n0 = bx * 128;
  const int wmq = (wv >> 1) * 4;
  const int wnq = (wv & 1) * 4;

  const _Float16* ApS[2];
  const _Float16* BpS[2];
#pragma unroll
  for (int i = 0; i < 2; ++i) {
    int mi = 2 * wv + i;
    int r = min(m0 + mi * 16 + fm, M - 1);
    ApS[i] = A + (size_t)r * K + k8;
    BpS[i] = Bt + (size_t)(n0 + mi * 16 + fm) * K + k8;
  }

  f32x4 acc[4][4] = {};
  const int nkc = K >> 5;

#pragma unroll
  for (int i = 0; i < 2; ++i) {
    int mi = 2 * wv + i;
    gload_lds16(ApS[i], &lds[0][mi * 512 + lane * 8]);
    gload_lds16(BpS[i], &lds[0][(8 + mi) * 512 + lane * 8]);
  }

  for (int kc = 0; kc < nkc; ++kc) {
    __syncthreads();
    if (kc + 1 < nkc) {
      _Float16* buf = lds[(kc + 1) & 1];
      int ko = (kc + 1) * 32;
#pragma unroll
      for (int i = 0; i < 2; ++i) {
        int mi = 2 * wv + i;
        gload_lds16(ApS[i] + ko, &buf[mi * 512 + lane * 8]);
        gload_lds16(BpS[i] + ko, &buf[(8 + mi) * 512 + lane * 8]);
      }
    }
    const _Float16* bb = lds[kc & 1];
    f16x8 a[4], b[4];
#pragma unroll
    for (int i = 0; i < 4; ++i) a[i] = *(const f16x8*)&bb[(wmq + i) * 512 + lane * 8];
#pragma unroll
    for (int i = 0; i < 4; ++i) b[i] = *(const f16x8*)&bb[(8 + wnq + i) * 512 + lane * 8];
#pragma unroll
    for (int mi = 0; mi < 4; ++mi)
#pragma unroll
      for (int ni = 0; ni < 4; ++ni)
        acc[mi][ni] = __builtin_amdgcn_mfma_f32_16x16x32_f16(a[mi], b[ni], acc[mi][ni], 0, 0, 0);
  }

  // epilogue: stage through per-wave LDS region, store coalesced f16x8
  __syncthreads();
  float bi[4];
#pragma unroll
  for (int ni = 0; ni < 4; ++ni) bi[ni] = bias[n0 + (wnq + ni) * 16 + fm];
  const int rq = (lane >> 4) * 4;
  float ssum[4] = {}, ssq[4] = {};
  _Float16* stg = ((_Float16*)lds) + wv * 4096;
#pragma unroll
  for (int mi = 0; mi < 4; ++mi) {
#pragma unroll
    for (int ni = 0; ni < 4; ++ni) {
#pragma unroll
      for (int r = 0; r < 4; ++r) {
        int lr = mi * 16 + rq + r;
        int row = m0 + (wv >> 1) * 64 + lr;
        float v = acc[mi][ni][r] + bi[ni];
        if (RELU) v = fmaxf(v, 0.f);
        if (row < M) {
          stg[lr * 64 + ni * 16 + fm] = (_Float16)v;
          if (STATS) { ssum[ni] += v; ssq[ni] += v * v; }
        }
      }
    }
  }
  {
    const int rr0 = lane >> 3;
    const int c8 = (lane & 7) * 8;
    const int bandc = n0 + wnq * 16;
    if (bandc < NREAL) {
#pragma unroll
      for (int rr = 0; rr < 8; ++rr) {
        int lr = rr * 8 + rr0;
        int row = m0 + (wv >> 1) * 64 + lr;
        if (row < M)
          *(f16x8*)&C[(size_t)row * ldC + bandc + c8] = *(const f16x8*)&stg[lr * 64 + c8];
      }
    }
  }
  if (STATS) {
    __syncthreads();
    float* sred = (float*)lds;
    if (t < 128) { sred[t] = 0.f; sred[128 + t] = 0.f; }
    __syncthreads();
    const int wn = (wv & 1) * 64;
#pragma unroll
    for (int ni = 0; ni < 4; ++ni) {
      atomicAdd(&sred[wn + ni * 16 + fm], ssum[ni]);
      atomicAdd(&sred[128 + wn + ni * 16 + fm], ssq[ni]);
    }
    __syncthreads();
    if (t < 128) {
      int gc = bx * 128 + t;
      atomicAdd(&stats[gc], sred[t]);
      atomicAdd(&stats[EMB_G + gc], sred[128 + t]);
    }
  }
}

// ---------------- readout ----------------

#define POOL_BLOCKS 784

__global__ __launch_bounds__(256) void pool2_kernel(const _Float16* __restrict__ h,
                                                    const int* __restrict__ gid,
                                                    float* __restrict__ graw) {
  const int w = (blockIdx.x * 256 + threadIdx.x) >> 6;
  const int lane = threadIdx.x & 63;
  const int NW = POOL_BLOCKS * 4;
  const int rpw = (NN + NW - 1) / NW;
  int r0 = w * rpw, r1 = min(r0 + rpw, NN);
  if (r0 >= r1 || lane >= 40) return;
  const f16x8* hb = (const f16x8*)h;
  float acc[8] = {};
  int curg = gid[r0];
  for (int r = r0; r < r1; ++r) {
    int g = gid[r];
    if (g != curg) {
#pragma unroll
      for (int i = 0; i < 8; ++i) {
        atomicAdd(&graw[curg * EMB_P + lane * 8 + i], acc[i]);
        acc[i] = 0.f;
      }
      curg = g;
    }
    f16x8 v = hb[(size_t)r * 40 + lane];
#pragma unroll
    for (int i = 0; i < 8; ++i) acc[i] += (float)v[i];
  }
#pragma unroll
  for (int i = 0; i < 8; ++i) atomicAdd(&graw[curg * EMB_P + lane * 8 + i], acc[i]);
}

// final: BN-finalize (last layer) into LDS, then count-divide + BN + 300x64 matvec
__global__ void final_kernel(const float* __restrict__ graw, const int* __restrict__ gid,
                             const float* __restrict__ stats, const float* __restrict__ gamma,
                             const float* __restrict__ beta, const float* __restrict__ wt,
                             const float* __restrict__ bt, float* __restrict__ out) {
  __shared__ float ssc[DEMB], ssh[DEMB];
  __shared__ int sb[2];
  int g = blockIdx.x, t = threadIdx.x;  // 64 threads
  for (int c = t; c < DEMB; c += 64) {
    float mu = stats[c] * (1.f / (float)NN);
    float var = fmaxf(stats[EMB_G + c] * (1.f / (float)NN) - mu * mu, 0.f);
    float s = gamma[c] * rsqrtf(var + BN_EPS_F);
    ssc[c] = s;
    ssh[c] = beta[c] - mu * s;
  }
  if (t < 2) {
    int target = g + t;
    int lo = 0, hi = NN;
    while (lo < hi) {
      int m = (lo + hi) >> 1;
      if (gid[m] < target) lo = m + 1; else hi = m;
    }
    sb[t] = lo;
  }
  __syncthreads();
  int cnt = sb[1] - sb[0];
  float inv = cnt > 0 ? 1.0f / (float)cnt : 0.f;
  float sh_on = cnt > 0 ? 1.0f : 0.f;
  float acc = bt[t];
  const float* row = graw + g * EMB_P;
  for (int k = 0; k < DEMB; ++k) {
    float gf = (row[k] * inv) * ssc[k] + sh_on * ssh[k];
    acc = fmaf(gf, wt[k * DOUT + t], acc);
  }
  out[g * DOUT + t] = acc;
}

// ---------------- launch ----------------

extern "C" void kernel_launch(void* const* d_in, const int* in_sizes, int n_in,
                              void* d_out, int out_size, void* d_ws, size_t ws_size,
                              hipStream_t stream) {
  const float* node_feats = (const float*)d_in[0];
  const float* edge_feats = (const float*)d_in[1];
  const int* src = (const int*)d_in[2];
  const int* dst = (const int*)d_in[3];
  const int* gid = (const int*)d_in[4];
  const float* w1_0 = (const float*)d_in[5];
  const float* b1_0 = (const float*)d_in[6];
  const float* w2_0 = (const float*)d_in[7];
  const float* b2_0 = (const float*)d_in[8];
  const float* gamma_0 = (const float*)d_in[9];
  const float* beta_0 = (const float*)d_in[10];
  const float* w1s = (const float*)d_in[11];
  const float* b1s = (const float*)d_in[12];
  const float* w2s = (const float*)d_in[13];
  const float* b2s = (const float*)d_in[14];
  const float* gammas = (const float*)d_in[15];
  const float* betas = (const float*)d_in[16];
  const float* wt = (const float*)d_in[17];
  const float* bt = (const float*)d_in[18];
  float* out = (float*)d_out;
  (void)in_sizes; (void)n_in; (void)out_size; (void)ws_size;

  char* ws = (char*)d_ws;
  size_t off = 0;
  auto carve = [&](size_t bytes) -> void* {
    void* p = ws + off;
    off += (bytes + 255) & ~(size_t)255;
    return p;
  };
  _Float16* P0 = (_Float16*)carve((size_t)NN * EMB_P * 2);   // agg (holds [N][32] for l0)
  _Float16* P1 = (_Float16*)carve((size_t)NN * EMB_P * 2);   // raw h2 (pre-BN)
  _Float16* Q  = (_Float16*)carve((size_t)NN * HID_P * 2);   // h1
  // zero-init region: esum, counts, graw, stats carved contiguously -> ONE memset
  size_t zbeg = off;
  float* esum   = (float*)carve((size_t)NN * 4);
  int* counts   = (int*)carve((size_t)NN * 4);
  float* graw   = (float*)carve((size_t)NG * EMB_P * 4);
  float* stats  = (float*)carve((size_t)5 * 2 * EMB_G * 4);  // 5 per-layer regions
  size_t zend = off;
  int* row_ptr  = (int*)carve((size_t)(NN + 1) * 4);
  int* cursor   = (int*)carve((size_t)NN * 4);
  int* csr_src  = (int*)carve((size_t)NE * 4);
  int* bsums    = (int*)carve((size_t)SCAN_BLK * 4);
  int* boffs    = (int*)carve((size_t)SCAN_BLK * 4);
  _Float16* w1t0 = (_Float16*)carve((size_t)HID_P * DIN_P * 2);
  _Float16* w1t  = (_Float16*)carve((size_t)4 * HID_P * EMB_P * 2);
  _Float16* w2t  = (_Float16*)carve((size_t)5 * EMB_G * HID_P * 2);
  float* b1p   = (float*)carve((size_t)5 * HID_P * 4);
  float* b2p   = (float*)carve((size_t)5 * EMB_G * 4);

  hipMemsetAsync(ws + zbeg, 0, zend - zbeg, stream);

  // CSR by dst + per-node edge-feature sums
  count_edges_kernel<<<(NE + 255) / 256, 256, 0, stream>>>(dst, edge_feats, counts, esum);
  scan_part1<<<SCAN_BLK, 256, 0, stream>>>(counts, bsums);
  scan_part2<<<1, 512, 0, stream>>>(bsums, boffs);
  scan_part3<<<SCAN_BLK, 256, 0, stream>>>(counts, boffs, row_ptr, cursor);
  scatter_kernel<<<(NE + 255) / 256, 256, 0, stream>>>(src, dst, cursor, csr_src);

  // all weight/bias repacks in one launch
  repack_all_kernel<<<(RT4 + 255) / 256, 256, 0, stream>>>(
      w1_0, w1s, w2_0, w2s, b1_0, b1s, b2_0, b2s, w1t0, w1t, w2t, b1p, b2p);

  const int MT = (NN + 127) / 128;           // 782 M-tiles
  const int MT8 = ((MT + 7) / 8) * 8;        // 784 (padded for XCD decode)
  const int spmm_blocks = (NN * 64 + 255) / 256;
  const int spmm0_blocks = (NN * 32 + 255) / 256;

  const float* ga_prev = nullptr;
  const float* be_prev = nullptr;
  float* stats_prev = nullptr;

  for (int l = 0; l < 5; ++l) {
    const _Float16* w1t_l = (l == 0) ? w1t0 : w1t + (size_t)(l - 1) * HID_P * EMB_P;
    const _Float16* w2t_l = w2t + (size_t)l * EMB_G * HID_P;
    const float* b1p_l = b1p + (size_t)l * HID_P;
    const float* b2p_l = b2p + (size_t)l * EMB_G;
    const float* ga = (l == 0) ? gamma_0 : gammas + (size_t)(l - 1) * DEMB;
    const float* be = (l == 0) ? beta_0 : betas + (size_t)(l - 1) * DEMB;
    float* stats_l = stats + (size_t)l * 2 * EMB_G;
    int K1 = (l == 0) ? DIN_P : EMB_P;

    if (l == 0) {
      spmm0_kernel<<<spmm0_blocks, 256, 0, stream>>>(node_feats, row_ptr, csr_src, esum, P0);
    } else {
      spmm_f16_kernel<<<spmm_blocks, 256, 0, stream>>>(
          P1, stats_prev, ga_prev, be_prev, row_ptr, csr_src, esum, P0);
    }

    gemm_pipe_kernel<true, false, 5><<<5 * MT8, 256, 0, stream>>>(
        P0, w1t_l, b1p_l, Q, NN, K1, HID_P, HID_P, MT, nullptr);

    gemm_pipe_kernel<false, true, 3><<<3 * MT8, 256, 0, stream>>>(
        Q, w2t_l, b2p_l, P1, NN, HID_P, EMB_P, EMB_P, MT, stats_l);

    stats_prev = stats_l;
    ga_prev = ga;
    be_prev = be;
  }

  pool2_kernel<<<POOL_BLOCKS, 256, 0, stream>>>(P1, gid, graw);
  final_kernel<<<NG, 64, 0, stream>>>(graw, gid, stats_prev, ga_prev, be_prev, wt, bt, out);
}

// Round 15
// 2083.852 us; speedup vs baseline: 1.2684x; 1.2684x over previous
//
#include <hip/hip_runtime.h>

#define NN 100000
#define NE 1600000
#define NG 128
#define DIN 20
#define DEMB 300
#define DHID 600
#define DOUT 64
// padded dims
#define DIN_P 32
#define EMB_P 320   // activation storage width (multiple of 64)
#define HID_P 640
#define EMB_G 384   // gemm2 N-dim padding (multiple of 128)
#define SCAN_BLK 392  // ceil(NN/256)

static const float BN_EPS_F = 1e-5f;

typedef _Float16 f16x8 __attribute__((ext_vector_type(8)));
typedef float f32x4 __attribute__((ext_vector_type(4)));

// async global->LDS, 16B per lane; LDS dst = wave-uniform base + lane*16
__device__ __forceinline__ void gload_lds16(const void* g, const void* l) {
  __builtin_amdgcn_global_load_lds(
      (const __attribute__((address_space(1))) unsigned int*)(unsigned long long)g,
      (__attribute__((address_space(3))) unsigned int*)(unsigned long long)(unsigned int)(unsigned long long)l,
      16, 0, 0);
}

// ---------------- CSR build (once per call) ----------------

__global__ void count_edges_kernel(const int* __restrict__ dst, const float* __restrict__ ef,
                                   int* __restrict__ counts, float* __restrict__ esum) {
  int e = blockIdx.x * blockDim.x + threadIdx.x;
  if (e >= NE) return;
  int v = dst[e];
  atomicAdd(&counts[v], 1);
  atomicAdd(&esum[v], ef[e]);
}

// 3-phase exclusive scan of counts -> row_ptr/cursor
__global__ __launch_bounds__(256) void scan_part1(const int* __restrict__ counts,
                                                  int* __restrict__ bsums) {
  __shared__ int red[256];
  int t = threadIdx.x;
  int i = blockIdx.x * 256 + t;
  red[t] = (i < NN) ? counts[i] : 0;
  __syncthreads();
  for (int s = 128; s > 0; s >>= 1) {
    if (t < s) red[t] += red[t + s];
    __syncthreads();
  }
  if (t == 0) bsums[blockIdx.x] = red[0];
}

__global__ __launch_bounds__(512) void scan_part2(const int* __restrict__ bsums,
                                                  int* __restrict__ boffs) {
  __shared__ int sc[512];
  int t = threadIdx.x;
  int v = (t < SCAN_BLK) ? bsums[t] : 0;
  sc[t] = v;
  __syncthreads();
  for (int off = 1; off < 512; off <<= 1) {
    int u = (t >= off) ? sc[t - off] : 0;
    __syncthreads();
    sc[t] += u;
    __syncthreads();
  }
  if (t < SCAN_BLK) boffs[t] = sc[t] - v;  // exclusive
}

__global__ __launch_bounds__(256) void scan_part3(const int* __restrict__ counts,
                                                  const int* __restrict__ boffs,
                                                  int* __restrict__ row_ptr,
                                                  int* __restrict__ cursor) {
  __shared__ int sc[256];
  int t = threadIdx.x;
  int i = blockIdx.x * 256 + t;
  int v = (i < NN) ? counts[i] : 0;
  sc[t] = v;
  __syncthreads();
  for (int off = 1; off < 256; off <<= 1) {
    int u = (t >= off) ? sc[t - off] : 0;
    __syncthreads();
    sc[t] += u;
    __syncthreads();
  }
  if (i < NN) {
    int excl = sc[t] - v + boffs[blockIdx.x];
    row_ptr[i] = excl;
    cursor[i] = excl;
  }
  if (i == NN - 1) row_ptr[NN] = NE;
}

__global__ void scatter_kernel(const int* __restrict__ src, const int* __restrict__ dst,
                               int* __restrict__ cursor, int* __restrict__ csr_src) {
  int e = blockIdx.x * blockDim.x + threadIdx.x;
  if (e >= NE) return;
  int pos = atomicAdd(&cursor[dst[e]], 1);
  csr_src[pos] = src[e];
}

// ---------------- ONE fused repack kernel: all weights + biases ----------------

#define RT0 (HID_P * DIN_P)                 // 20480
#define RT1 (RT0 + 4 * HID_P * EMB_P)       // 839680
#define RT2 (RT1 + 5 * EMB_G * HID_P)       // 2068480
#define RT3 (RT2 + 5 * HID_P)               // 2071680
#define RT4 (RT3 + 5 * EMB_G)               // 2073600

__global__ void repack_all_kernel(const float* __restrict__ w1_0, const float* __restrict__ w1s,
                                  const float* __restrict__ w2_0, const float* __restrict__ w2s,
                                  const float* __restrict__ b1_0, const float* __restrict__ b1s,
                                  const float* __restrict__ b2_0, const float* __restrict__ b2s,
                                  _Float16* __restrict__ w1t0, _Float16* __restrict__ w1t,
                                  _Float16* __restrict__ w2t, float* __restrict__ b1p,
                                  float* __restrict__ b2p) {
  int idx = blockIdx.x * blockDim.x + threadIdx.x;
  if (idx >= RT4) return;
  if (idx < RT0) {
    int n = idx / DIN_P, k = idx - n * DIN_P;
    float v = (n < DHID && k < DIN) ? w1_0[(size_t)k * DHID + n] : 0.f;
    w1t0[idx] = (_Float16)v;
  } else if (idx < RT1) {
    int r = idx - RT0;
    int l = r / (HID_P * EMB_P);
    int q = r - l * (HID_P * EMB_P);
    int n = q / EMB_P, k = q - n * EMB_P;
    const float* w = w1s + (size_t)l * DEMB * DHID;
    float v = (n < DHID && k < DEMB) ? w[(size_t)k * DHID + n] : 0.f;
    w1t[r] = (_Float16)v;
  } else if (idx < RT2) {
    int r = idx - RT1;
    int l = r / (EMB_G * HID_P);
    int q = r - l * (EMB_G * HID_P);
    int n = q / HID_P, k = q - n * HID_P;
    const float* w = (l == 0) ? w2_0 : w2s + (size_t)(l - 1) * DHID * DEMB;
    float v = (n < DEMB && k < DHID) ? w[(size_t)k * DEMB + n] : 0.f;
    w2t[r] = (_Float16)v;
  } else if (idx < RT3) {
    int r = idx - RT2;
    int l = r / HID_P, i = r - l * HID_P;
    const float* b = (l == 0) ? b1_0 : b1s + (size_t)(l - 1) * DHID;
    b1p[r] = (i < DHID) ? b[i] : 0.f;
  } else {
    int r = idx - RT3;
    int l = r / EMB_G, i = r - l * EMB_G;
    const float* b = (l == 0) ? b2_0 : b2s + (size_t)(l - 1) * DEMB;
    b2p[r] = (i < DEMB) ? b[i] : 0.f;
  }
}

// ---------------- layer-0 spmm: fp32 x[N][20] -> fp16 agg0[N][32], half-wave per node ----

__global__ __launch_bounds__(256) void spmm0_kernel(const float* __restrict__ x,
                                                    const int* __restrict__ row_ptr,
                                                    const int* __restrict__ csr_src,
                                                    const float* __restrict__ esum,
                                                    _Float16* __restrict__ out) {
  int node = (blockIdx.x * blockDim.x + threadIdx.x) >> 5;
  int lane = threadIdx.x & 31;
  if (node >= NN) return;
  int beg = row_ptr[node], end = row_ptr[node + 1];
  float acc = 0.f;
  int j = beg;
  for (; j + 1 < end; j += 2) {
    int s0 = csr_src[j], s1 = csr_src[j + 1];
    if (lane < DIN) {
      acc += x[(size_t)s0 * DIN + lane];
      acc += x[(size_t)s1 * DIN + lane];
    }
  }
  if (j < end) {
    int s0 = csr_src[j];
    if (lane < DIN) acc += x[(size_t)s0 * DIN + lane];
  }
  float v = (lane < DIN) ? acc + esum[node] : 0.f;
  out[(size_t)node * DIN_P + lane] = (_Float16)v;
}

// ---------------- fused spmm (layers 1..4): R13-exact — gather raw h2 fp16, apply
// precomputed scale/shift on the fly (44 VGPR, max loads in flight) ----

__global__ __launch_bounds__(256) void spmm_f16_kernel(const _Float16* __restrict__ x,
                                                       const float* __restrict__ scale,
                                                       const float* __restrict__ shift,
                                                       const int* __restrict__ row_ptr,
                                                       const int* __restrict__ csr_src,
                                                       const float* __restrict__ esum,
                                                       _Float16* __restrict__ out) {
  int wid = (blockIdx.x * blockDim.x + threadIdx.x) >> 6;
  int lane = threadIdx.x & 63;
  if (wid >= NN) return;
  int beg = row_ptr[wid], end = row_ptr[wid + 1];
  float deg = (float)(end - beg);
  float es = esum[wid];
  if (lane >= 40) return;
  const f16x8* xb = (const f16x8*)x;
  float acc[8] = {};
  int j = beg;
  for (; j + 7 < end; j += 8) {
    int s0 = csr_src[j + 0], s1 = csr_src[j + 1], s2 = csr_src[j + 2], s3 = csr_src[j + 3];
    int s4 = csr_src[j + 4], s5 = csr_src[j + 5], s6 = csr_src[j + 6], s7 = csr_src[j + 7];
    f16x8 v0 = xb[(size_t)s0 * 40 + lane];
    f16x8 v1 = xb[(size_t)s1 * 40 + lane];
    f16x8 v2 = xb[(size_t)s2 * 40 + lane];
    f16x8 v3 = xb[(size_t)s3 * 40 + lane];
    f16x8 v4 = xb[(size_t)s4 * 40 + lane];
    f16x8 v5 = xb[(size_t)s5 * 40 + lane];
    f16x8 v6 = xb[(size_t)s6 * 40 + lane];
    f16x8 v7 = xb[(size_t)s7 * 40 + lane];
#pragma unroll
    for (int i = 0; i < 8; ++i) {
      acc[i] += ((float)v0[i] + (float)v1[i]) + ((float)v2[i] + (float)v3[i]) +
                ((float)v4[i] + (float)v5[i]) + ((float)v6[i] + (float)v7[i]);
    }
  }
  for (; j < end; ++j) {
    f16x8 v0 = xb[(size_t)csr_src[j] * 40 + lane];
#pragma unroll
    for (int i = 0; i < 8; ++i) acc[i] += (float)v0[i];
  }
  int c = lane * 8;
  f16x8 o;
#pragma unroll
  for (int i = 0; i < 8; ++i)
    o[i] = (_Float16)(acc[i] * scale[c + i] + deg * shift[c + i] + es);
  ((f16x8*)(out))[(size_t)wid * 40 + lane] = o;
}

// ---------------- pipelined 128x128 MFMA GEMM + XCD swizzle + LDS-staged epilogue (R13) ----

template <bool RELU, bool STATS, int GX>
__global__ __launch_bounds__(256, 4) void gemm_pipe_kernel(const _Float16* __restrict__ A,
                                                           const _Float16* __restrict__ Bt,
                                                           const float* __restrict__ bias,
                                                           _Float16* __restrict__ C,
                                                           int M, int K, int ldC, int NREAL,
                                                           int MT,
                                                           float* __restrict__ stats) {
  __shared__ __align__(16) _Float16 lds[2][16 * 512];  // 2 x 16 KB; reused as 4 x 8 KB epilogue staging
  const int id = blockIdx.x;
  const int grp = id / (GX * 8);
  const int rem = id - grp * (GX * 8);
  const int bx = rem >> 3;
  const int by = grp * 8 + (rem & 7);
  if (by >= MT) return;

  const int t = threadIdx.x;
  const int wv = t >> 6;
  const int lane = t & 63;
  const int fm = lane & 15;
  const int k8 = (lane >> 4) * 8;
  const int m0 = by * 128;
  const int n0 = bx * 128;
  const int wmq = (wv >> 1) * 4;
  const int wnq = (wv & 1) * 4;

  const _Float16* ApS[2];
  const _Float16* BpS[2];
#pragma unroll
  for (int i = 0; i < 2; ++i) {
    int mi = 2 * wv + i;
    int r = min(m0 + mi * 16 + fm, M - 1);
    ApS[i] = A + (size_t)r * K + k8;
    BpS[i] = Bt + (size_t)(n0 + mi * 16 + fm) * K + k8;
  }

  f32x4 acc[4][4] = {};
  const int nkc = K >> 5;

#pragma unroll
  for (int i = 0; i < 2; ++i) {
    int mi = 2 * wv + i;
    gload_lds16(ApS[i], &lds[0][mi * 512 + lane * 8]);
    gload_lds16(BpS[i], &lds[0][(8 + mi) * 512 + lane * 8]);
  }

  for (int kc = 0; kc < nkc; ++kc) {
    __syncthreads();
    if (kc + 1 < nkc) {
      _Float16* buf = lds[(kc + 1) & 1];
      int ko = (kc + 1) * 32;
#pragma unroll
      for (int i = 0; i < 2; ++i) {
        int mi = 2 * wv + i;
        gload_lds16(ApS[i] + ko, &buf[mi * 512 + lane * 8]);
        gload_lds16(BpS[i] + ko, &buf[(8 + mi) * 512 + lane * 8]);
      }
    }
    const _Float16* bb = lds[kc & 1];
    f16x8 a[4], b[4];
#pragma unroll
    for (int i = 0; i < 4; ++i) a[i] = *(const f16x8*)&bb[(wmq + i) * 512 + lane * 8];
#pragma unroll
    for (int i = 0; i < 4; ++i) b[i] = *(const f16x8*)&bb[(8 + wnq + i) * 512 + lane * 8];
#pragma unroll
    for (int mi = 0; mi < 4; ++mi)
#pragma unroll
      for (int ni = 0; ni < 4; ++ni)
        acc[mi][ni] = __builtin_amdgcn_mfma_f32_16x16x32_f16(a[mi], b[ni], acc[mi][ni], 0, 0, 0);
  }

  // epilogue: stage through per-wave LDS region, store coalesced f16x8
  __syncthreads();
  float bi[4];
#pragma unroll
  for (int ni = 0; ni < 4; ++ni) bi[ni] = bias[n0 + (wnq + ni) * 16 + fm];
  const int rq = (lane >> 4) * 4;
  float ssum[4] = {}, ssq[4] = {};
  _Float16* stg = ((_Float16*)lds) + wv * 4096;
#pragma unroll
  for (int mi = 0; mi < 4; ++mi) {
#pragma unroll
    for (int ni = 0; ni < 4; ++ni) {
#pragma unroll
      for (int r = 0; r < 4; ++r) {
        int lr = mi * 16 + rq + r;
        int row = m0 + (wv >> 1) * 64 + lr;
        float v = acc[mi][ni][r] + bi[ni];
        if (RELU) v = fmaxf(v, 0.f);
        if (row < M) {
          stg[lr * 64 + ni * 16 + fm] = (_Float16)v;
          if (STATS) { ssum[ni] += v; ssq[ni] += v * v; }
        }
      }
    }
  }
  {
    const int rr0 = lane >> 3;
    const int c8 = (lane & 7) * 8;
    const int bandc = n0 + wnq * 16;
    if (bandc < NREAL) {
#pragma unroll
      for (int rr = 0; rr < 8; ++rr) {
        int lr = rr * 8 + rr0;
        int row = m0 + (wv >> 1) * 64 + lr;
        if (row < M)
          *(f16x8*)&C[(size_t)row * ldC + bandc + c8] = *(const f16x8*)&stg[lr * 64 + c8];
      }
    }
  }
  if (STATS) {
    __syncthreads();
    float* sred = (float*)lds;
    if (t < 128) { sred[t] = 0.f; sred[128 + t] = 0.f; }
    __syncthreads();
    const int wn = (wv & 1) * 64;
#pragma unroll
    for (int ni = 0; ni < 4; ++ni) {
      atomicAdd(&sred[wn + ni * 16 + fm], ssum[ni]);
      atomicAdd(&sred[128 + wn + ni * 16 + fm], ssq[ni]);
    }
    __syncthreads();
    if (t < 128) {
      int gc = bx * 128 + t;
      atomicAdd(&stats[gc], sred[t]);
      atomicAdd(&stats[EMB_G + gc], sred[128 + t]);
    }
  }
}

// ---------------- BN finalize ----------------

__global__ void bn_finalize_kernel(const float* __restrict__ stats, const float* __restrict__ gamma,
                                   const float* __restrict__ beta, float* __restrict__ scale,
                                   float* __restrict__ shift) {
  int c = threadIdx.x;
  if (c >= EMB_P) return;
  if (c < DEMB) {
    float mu = stats[c] / (float)NN;
    float var = fmaxf(stats[EMB_G + c] / (float)NN - mu * mu, 0.f);
    float sc = gamma[c] * rsqrtf(var + BN_EPS_F);
    scale[c] = sc;
    shift[c] = beta[c] - mu * sc;
  } else {
    scale[c] = 0.f;
    shift[c] = 0.f;
  }
}

// ---------------- readout ----------------

#define POOL_BLOCKS 784

__global__ __launch_bounds__(256) void pool2_kernel(const _Float16* __restrict__ h,
                                                    const int* __restrict__ gid,
                                                    float* __restrict__ graw) {
  const int w = (blockIdx.x * 256 + threadIdx.x) >> 6;
  const int lane = threadIdx.x & 63;
  const int NW = POOL_BLOCKS * 4;
  const int rpw = (NN + NW - 1) / NW;
  int r0 = w * rpw, r1 = min(r0 + rpw, NN);
  if (r0 >= r1 || lane >= 40) return;
  const f16x8* hb = (const f16x8*)h;
  float acc[8] = {};
  int curg = gid[r0];
  for (int r = r0; r < r1; ++r) {
    int g = gid[r];
    if (g != curg) {
#pragma unroll
      for (int i = 0; i < 8; ++i) {
        atomicAdd(&graw[curg * EMB_P + lane * 8 + i], acc[i]);
        acc[i] = 0.f;
      }
      curg = g;
    }
    f16x8 v = hb[(size_t)r * 40 + lane];
#pragma unroll
    for (int i = 0; i < 8; ++i) acc[i] += (float)v[i];
  }
#pragma unroll
  for (int i = 0; i < 8; ++i) atomicAdd(&graw[curg * EMB_P + lane * 8 + i], acc[i]);
}

__global__ void final_kernel(const float* __restrict__ graw, const int* __restrict__ gid,
                             const float* __restrict__ scale, const float* __restrict__ shift,
                             const float* __restrict__ wt, const float* __restrict__ bt,
                             float* __restrict__ out) {
  int g = blockIdx.x, t = threadIdx.x;  // 64 threads
  __shared__ int sb[2];
  if (t < 2) {
    int target = g + t;
    int lo = 0, hi = NN;
    while (lo < hi) {
      int m = (lo + hi) >> 1;
      if (gid[m] < target) lo = m + 1; else hi = m;
    }
    sb[t] = lo;
  }
  __syncthreads();
  int cnt = sb[1] - sb[0];
  float inv = cnt > 0 ? 1.0f / (float)cnt : 0.f;
  float sh_on = cnt > 0 ? 1.0f : 0.f;
  float acc = bt[t];
  const float* row = graw + g * EMB_P;
  for (int k = 0; k < DEMB; ++k) {
    float gf = row[k] * inv * scale[k] + sh_on * shift[k];
    acc = fmaf(gf, wt[k * DOUT + t], acc);
  }
  out[g * DOUT + t] = acc;
}

// ---------------- launch ----------------

extern "C" void kernel_launch(void* const* d_in, const int* in_sizes, int n_in,
                              void* d_out, int out_size, void* d_ws, size_t ws_size,
                              hipStream_t stream) {
  const float* node_feats = (const float*)d_in[0];
  const float* edge_feats = (const float*)d_in[1];
  const int* src = (const int*)d_in[2];
  const int* dst = (const int*)d_in[3];
  const int* gid = (const int*)d_in[4];
  const float* w1_0 = (const float*)d_in[5];
  const float* b1_0 = (const float*)d_in[6];
  const float* w2_0 = (const float*)d_in[7];
  const float* b2_0 = (const float*)d_in[8];
  const float* gamma_0 = (const float*)d_in[9];
  const float* beta_0 = (const float*)d_in[10];
  const float* w1s = (const float*)d_in[11];
  const float* b1s = (const float*)d_in[12];
  const float* w2s = (const float*)d_in[13];
  const float* b2s = (const float*)d_in[14];
  const float* gammas = (const float*)d_in[15];
  const float* betas = (const float*)d_in[16];
  const float* wt = (const float*)d_in[17];
  const float* bt = (const float*)d_in[18];
  float* out = (float*)d_out;
  (void)in_sizes; (void)n_in; (void)out_size; (void)ws_size;

  char* ws = (char*)d_ws;
  size_t off = 0;
  auto carve = [&](size_t bytes) -> void* {
    void* p = ws + off;
    off += (bytes + 255) & ~(size_t)255;
    return p;
  };
  _Float16* P0 = (_Float16*)carve((size_t)NN * EMB_P * 2);   // agg (holds [N][32] for l0)
  _Float16* P1 = (_Float16*)carve((size_t)NN * EMB_P * 2);   // raw h2 (pre-BN)
  _Float16* Q  = (_Float16*)carve((size_t)NN * HID_P * 2);   // h1
  // zero-init region: esum, counts, graw, stats contiguous -> ONE memset
  size_t zbeg = off;
  float* esum   = (float*)carve((size_t)NN * 4);
  int* counts   = (int*)carve((size_t)NN * 4);
  float* graw   = (float*)carve((size_t)NG * EMB_P * 4);
  float* stats  = (float*)carve((size_t)5 * 2 * EMB_G * 4);  // 5 per-layer regions
  size_t zend = off;
  int* row_ptr  = (int*)carve((size_t)(NN + 1) * 4);
  int* cursor   = (int*)carve((size_t)NN * 4);
  int* csr_src  = (int*)carve((size_t)NE * 4);
  int* bsums    = (int*)carve((size_t)SCAN_BLK * 4);
  int* boffs    = (int*)carve((size_t)SCAN_BLK * 4);
  _Float16* w1t0 = (_Float16*)carve((size_t)HID_P * DIN_P * 2);
  _Float16* w1t  = (_Float16*)carve((size_t)4 * HID_P * EMB_P * 2);
  _Float16* w2t  = (_Float16*)carve((size_t)5 * EMB_G * HID_P * 2);
  float* b1p   = (float*)carve((size_t)5 * HID_P * 4);
  float* b2p   = (float*)carve((size_t)5 * EMB_G * 4);
  float* scale = (float*)carve(EMB_P * 4);
  float* shift = (float*)carve(EMB_P * 4);

  hipMemsetAsync(ws + zbeg, 0, zend - zbeg, stream);

  // CSR by dst + per-node edge-feature sums
  count_edges_kernel<<<(NE + 255) / 256, 256, 0, stream>>>(dst, edge_feats, counts, esum);
  scan_part1<<<SCAN_BLK, 256, 0, stream>>>(counts, bsums);
  scan_part2<<<1, 512, 0, stream>>>(bsums, boffs);
  scan_part3<<<SCAN_BLK, 256, 0, stream>>>(counts, boffs, row_ptr, cursor);
  scatter_kernel<<<(NE + 255) / 256, 256, 0, stream>>>(src, dst, cursor, csr_src);

  // all weight/bias repacks in one launch
  repack_all_kernel<<<(RT4 + 255) / 256, 256, 0, stream>>>(
      w1_0, w1s, w2_0, w2s, b1_0, b1s, b2_0, b2s, w1t0, w1t, w2t, b1p, b2p);

  const int MT = (NN + 127) / 128;           // 782 M-tiles
  const int MT8 = ((MT + 7) / 8) * 8;        // 784 (padded for XCD decode)
  const int spmm_blocks = (NN * 64 + 255) / 256;
  const int spmm0_blocks = (NN * 32 + 255) / 256;

  for (int l = 0; l < 5; ++l) {
    const _Float16* w1t_l = (l == 0) ? w1t0 : w1t + (size_t)(l - 1) * HID_P * EMB_P;
    const _Float16* w2t_l = w2t + (size_t)l * EMB_G * HID_P;
    const float* b1p_l = b1p + (size_t)l * HID_P;
    const float* b2p_l = b2p + (size_t)l * EMB_G;
    const float* ga = (l == 0) ? gamma_0 : gammas + (size_t)(l - 1) * DEMB;
    const float* be = (l == 0) ? beta_0 : betas + (size_t)(l - 1) * DEMB;
    float* stats_l = stats + (size_t)l * 2 * EMB_G;
    int K1 = (l == 0) ? DIN_P : EMB_P;

    if (l == 0) {
      spmm0_kernel<<<spmm0_blocks, 256, 0, stream>>>(node_feats, row_ptr, csr_src, esum, P0);
    } else {
      spmm_f16_kernel<<<spmm_blocks, 256, 0, stream>>>(
          P1, scale, shift, row_ptr, csr_src, esum, P0);
    }

    gemm_pipe_kernel<true, false, 5><<<5 * MT8, 256, 0, stream>>>(
        P0, w1t_l, b1p_l, Q, NN, K1, HID_P, HID_P, MT, nullptr);

    gemm_pipe_kernel<false, true, 3><<<3 * MT8, 256, 0, stream>>>(
        Q, w2t_l, b2p_l, P1, NN, HID_P, EMB_P, EMB_P, MT, stats_l);

    bn_finalize_kernel<<<1, EMB_P, 0, stream>>>(stats_l, ga, be, scale, shift);
  }

  pool2_kernel<<<POOL_BLOCKS, 256, 0, stream>>>(P1, gid, graw);
  final_kernel<<<NG, 64, 0, stream>>>(graw, gid, scale, shift, wt, bt, out);
}